// Round 14
// baseline (79.378 us; speedup 1.0000x reference)
//
#include <hip/hip_runtime.h>

#define NPTS 4096
#define NB   8
#define TOT  (2 * NB * NPTS)   // 65536 rows (dir*batch*point)

typedef __attribute__((ext_vector_type(8))) short          bf16x8;
typedef __attribute__((ext_vector_type(8))) unsigned short u16x8;
typedef __attribute__((ext_vector_type(4))) float          f32x4;

__device__ __forceinline__ unsigned short bf16_rne(float f) {
    unsigned u = __float_as_uint(f);
    u += 0x7FFFu + ((u >> 16) & 1u);
    return (unsigned short)(u >> 16);
}
__device__ __forceinline__ float bf16_f(unsigned short s) {
    return __uint_as_float(((unsigned)s) << 16);
}

// s(i,j) = ah.bh(3) + al.bh(3) + ah.bl(3) + 1*hh + 1*hl : 11 slots of K=32,
// slots 11..31 zero. Numerics verified on-HW R7/R9/R13 (absmax ~0).
// 16x16x32 fragment order: lane = point(0..15) + 16*kquarter(0..3),
// 8 consecutive k-slots (16 B) per lane. Tile = 16 pts = 1 KB.
// Per cloud: 256 tiles = 256 KB (cloud stride 1<<18).

// ---------------- pass 0: A-ext + B-ext fragments + h + init ----------------
__global__ __launch_bounds__(256) void prep_kernel(
    const float* __restrict__ x, const float* __restrict__ y,
    unsigned short* __restrict__ Aform, unsigned short* __restrict__ Bform,
    float* __restrict__ h32, unsigned* __restrict__ smax,
    float* __restrict__ out)
{
    int i   = blockIdx.x * 256 + threadIdx.x;   // 0..65535
    int cid = i >> 12;                          // 0..7: x[b], 8..15: y[b]
    int p   = i & 4095;
    const float* src = (cid < 8) ? x + ((size_t)cid * NPTS + p) * 3
                                 : y + ((size_t)(cid - 8) * NPTS + p) * 3;
    float c0 = src[0], c1 = src[1], c2 = src[2];
    float h  = -0.5f * (c0 * c0 + c1 * c1 + c2 * c2);

    unsigned short h0 = bf16_rne(c0), h1 = bf16_rne(c1), h2 = bf16_rne(c2);
    unsigned short l0 = bf16_rne(c0 - bf16_f(h0));
    unsigned short l1 = bf16_rne(c1 - bf16_f(h1));
    unsigned short l2 = bf16_rne(c2 - bf16_f(h2));
    unsigned short hh = bf16_rne(h);
    unsigned short hl = bf16_rne(h - bf16_f(hh));
    const unsigned short ONE = 0x3F80;

    u16x8 a0q, a1q, b0q, b1q, zq;
    a0q[0]=h0; a0q[1]=h1; a0q[2]=h2; a0q[3]=l0; a0q[4]=l1; a0q[5]=l2; a0q[6]=h0; a0q[7]=h1;
    a1q[0]=h2; a1q[1]=ONE; a1q[2]=ONE; a1q[3]=0; a1q[4]=0; a1q[5]=0; a1q[6]=0; a1q[7]=0;
    b0q[0]=h0; b0q[1]=h1; b0q[2]=h2; b0q[3]=h0; b0q[4]=h1; b0q[5]=h2; b0q[6]=l0; b0q[7]=l1;
    b1q[0]=l2; b1q[1]=hh; b1q[2]=hl; b1q[3]=0; b1q[4]=0; b1q[5]=0; b1q[6]=0; b1q[7]=0;
    #pragma unroll
    for (int e = 0; e < 8; ++e) zq[e] = 0;

    int u = p >> 4, pos = p & 15;
    size_t tb = ((size_t)cid << 18) + (size_t)u * 1024;
    char* A = (char*)Aform + tb;
    char* B = (char*)Bform + tb;
    // quarter q lives at (q*16 + pos)*16
    *(u16x8*)(A + (0  + pos) * 16) = a0q;
    *(u16x8*)(A + (16 + pos) * 16) = a1q;
    *(u16x8*)(A + (32 + pos) * 16) = zq;
    *(u16x8*)(A + (48 + pos) * 16) = zq;
    *(u16x8*)(B + (0  + pos) * 16) = b0q;
    *(u16x8*)(B + (16 + pos) * 16) = b1q;
    *(u16x8*)(B + (32 + pos) * 16) = zq;
    *(u16x8*)(B + (48 + pos) * 16) = zq;

    h32[i]  = h;
    smax[i] = 0u;        // below any order-mapped float
    if (i == 0) *out = 0.f;
}

// ---------------- pass 1: 16x16x32 MFMA chamfer core ----------------
// grid = 16 clouds * 16 i-blocks * 4 j-quarters = 1024 blocks (4/CU).
// Wave: 4 i-tiles (64 rows) x 64 j-tiles (1024 pts), j-step 4.
// Tiny C/D (4 regs) keeps all accumulators in arch VGPRs (~110 live)
// at __launch_bounds__(256,4): 16 waves/CU, no AGPR shuttling, no spill.
__global__ __launch_bounds__(256, 4) void chamfer_mfma(
    const unsigned short* __restrict__ Aform,
    const unsigned short* __restrict__ Bform,
    unsigned* __restrict__ smax)
{
    __shared__ float ebuf[4][64 * 17];   // 17408 B, per-wave regions

    const int bid  = blockIdx.x;
    const int dirb = bid >> 6;        // 0..15 (A-cloud id)
    const int sub  = bid & 63;
    const int iblk = sub >> 2;        // 0..15 (256 rows each)
    const int jq   = sub & 3;         // 0..3  (1024 j pts)

    const int tid = threadIdx.x;
    const int w   = tid >> 6;         // wave 0..3
    const int l   = tid & 63;

    const char* Abase = (const char*)Aform + ((size_t)dirb << 18);
    const char* Bbase = (const char*)Bform + ((size_t)(dirb ^ 8) << 18);

    // A fragments: i-tiles iblk*16 + w*4 + t (16 rows each)
    const int it0 = iblk * 16 + w * 4;
    bf16x8 afr[4];
    #pragma unroll
    for (int t = 0; t < 4; ++t)
        afr[t] = *(const bf16x8*)(Abase + (size_t)(it0 + t) * 1024 + (size_t)l * 16);

    f32x4 zc = {0.f, 0.f, 0.f, 0.f};
    f32x4 run[4];
    #pragma unroll
    for (int t = 0; t < 4; ++t)
        #pragma unroll
        for (int r = 0; r < 4; ++r) run[t][r] = -3.0e38f;

    const char* Bq = Bbase + (size_t)(jq * 64) * 1024 + (size_t)l * 16;

    #pragma unroll 1
    for (int jj = 0; jj < 64; jj += 4) {
        bf16x8 b0 = *(const bf16x8*)(Bq + (size_t)jj * 1024);
        bf16x8 b1 = *(const bf16x8*)(Bq + (size_t)jj * 1024 + 1024);
        bf16x8 b2 = *(const bf16x8*)(Bq + (size_t)jj * 1024 + 2048);
        bf16x8 b3 = *(const bf16x8*)(Bq + (size_t)jj * 1024 + 3072);
        // pass A: j-tiles jj, jj+1  (8 MFMA, 32 dest regs max)
        #pragma unroll
        for (int t = 0; t < 4; ++t) {
            f32x4 d0 = __builtin_amdgcn_mfma_f32_16x16x32_bf16(afr[t], b0, zc, 0, 0, 0);
            f32x4 d1 = __builtin_amdgcn_mfma_f32_16x16x32_bf16(afr[t], b1, zc, 0, 0, 0);
            #pragma unroll
            for (int r = 0; r < 4; ++r)
                run[t][r] = fmaxf(fmaxf(d0[r], d1[r]), run[t][r]);   // v_max3_f32
        }
        // pass B: j-tiles jj+2, jj+3
        #pragma unroll
        for (int t = 0; t < 4; ++t) {
            f32x4 d2 = __builtin_amdgcn_mfma_f32_16x16x32_bf16(afr[t], b2, zc, 0, 0, 0);
            f32x4 d3 = __builtin_amdgcn_mfma_f32_16x16x32_bf16(afr[t], b3, zc, 0, 0, 0);
            #pragma unroll
            for (int r = 0; r < 4; ++r)
                run[t][r] = fmaxf(fmaxf(d2[r], d3[r]), run[t][r]);
        }
    }

    // ---- epilogue: C/D map col=l&15, row=(l>>4)*4+r (HW-verified) ----
    const int q = l >> 4, col = l & 15;
    #pragma unroll
    for (int t = 0; t < 4; ++t)
        #pragma unroll
        for (int r = 0; r < 4; ++r)
            ebuf[w][(t * 16 + q * 4 + r) * 17 + col] = run[t][r];
    __syncthreads();

    // thread l reduces its wave's local row l over 16 cols (stride 17: 2-way)
    float m = ebuf[w][l * 17];
    #pragma unroll
    for (int k = 1; k < 16; ++k) m = fmaxf(m, ebuf[w][l * 17 + k]);
    int idx = dirb * 4096 + iblk * 256 + w * 64 + l;
    unsigned bits = __float_as_uint(m);
    unsigned mu = (bits & 0x80000000u) ? ~bits : (bits | 0x80000000u);
    atomicMax(&smax[idx], mu);
}

// ---------------- pass 2: unmap, add h_a, sum ----------------
__global__ __launch_bounds__(256) void reduce_kernel(
    const unsigned* __restrict__ smax,
    const float* __restrict__ h32,
    float* __restrict__ out)
{
    const int stride = 64 * 256;
    int tid = blockIdx.x * 256 + threadIdx.x;
    float s = 0.f;
    for (int k = tid; k < TOT; k += stride) {
        unsigned u = smax[k];
        unsigned bits = (u & 0x80000000u) ? (u & 0x7FFFFFFFu) : ~u;
        s += __uint_as_float(bits) + h32[k];   // smax + h_a
    }

    #pragma unroll
    for (int off = 32; off > 0; off >>= 1)
        s += __shfl_down(s, off);

    __shared__ float redb[4];
    const int lane = threadIdx.x & 63, wave = threadIdx.x >> 6;
    if (lane == 0) redb[wave] = s;
    __syncthreads();
    if (threadIdx.x == 0) {
        float t = redb[0] + redb[1] + redb[2] + redb[3];
        // min_d = -2*(smax + h_a); loss = 0.005 * sum / 32768
        atomicAdd(out, t * (-2.0f * 0.005f / 32768.f));
    }
}

extern "C" void kernel_launch(void* const* d_in, const int* in_sizes, int n_in,
                              void* d_out, int out_size, void* d_ws, size_t ws_size,
                              hipStream_t stream) {
    const float* x = (const float*)d_in[0];
    const float* y = (const float*)d_in[1];
    float* out = (float*)d_out;

    unsigned short* Aform = (unsigned short*)d_ws;                          // 4 MB
    unsigned short* Bform = (unsigned short*)((char*)d_ws + (4u << 20));    // 4 MB
    float*          h32   = (float*)((char*)d_ws + (8u << 20));             // 256 KB
    unsigned*       smax  = (unsigned*)((char*)d_ws + (8u << 20) + (256u << 10));

    prep_kernel<<<dim3(TOT / 256), dim3(256), 0, stream>>>(x, y, Aform, Bform, h32, smax, out);
    chamfer_mfma<<<dim3(1024), dim3(256), 0, stream>>>(Aform, Bform, smax);
    reduce_kernel<<<dim3(64), dim3(256), 0, stream>>>(smax, h32, out);
}

// Round 15
// 70.400 us; speedup vs baseline: 1.1275x; 1.1275x over previous
//
#include <hip/hip_runtime.h>

#define NPTS 4096
#define NB   8
#define TOT  (2 * NB * NPTS)   // 65536 rows (dir*batch*point)

typedef __attribute__((ext_vector_type(8)))  short          bf16x8;
typedef __attribute__((ext_vector_type(8)))  unsigned short u16x8;
typedef __attribute__((ext_vector_type(16))) float          f32x16;

__device__ __forceinline__ unsigned short bf16_rne(float f) {
    unsigned u = __float_as_uint(f);
    u += 0x7FFFu + ((u >> 16) & 1u);
    return (unsigned short)(u >> 16);
}
__device__ __forceinline__ float bf16_f(unsigned short s) {
    return __uint_as_float(((unsigned)s) << 16);
}

// s(i,j) = ah.bh(3) + al.bh(3) + ah.bl(3) + 1*hh + 1*hl   (11 K-slots of 16)
// A slots: [ah0,ah1,ah2, al0,al1,al2, ah0,ah1 | ah2, 1, 1, 0,0,0,0,0]
// B slots: [bh0,bh1,bh2, bh0,bh1,bh2, bl0,bl1 | bl2, hh, hl, 0,0,0,0,0]
// 32x32x16 operand layout: lane l -> point (32u + (l&31)), k-slots 8*(l>>5)..+7.
// All verified on-HW R7/R9/R13 (absmax ~0).

// ---------------- pass 0: B fragments + smax init + out init ----------------
__global__ __launch_bounds__(256) void prep_b(
    const float* __restrict__ x, const float* __restrict__ y,
    unsigned short* __restrict__ Bform, unsigned* __restrict__ smax,
    float* __restrict__ out)
{
    int i   = blockIdx.x * 256 + threadIdx.x;   // 0..65535
    int cid = i >> 12;                          // 0..7: x[b], 8..15: y[b]
    int p   = i & 4095;
    const float* src = (cid < 8) ? x + ((size_t)cid * NPTS + p) * 3
                                 : y + ((size_t)(cid - 8) * NPTS + p) * 3;
    float c0 = src[0], c1 = src[1], c2 = src[2];
    float h  = -0.5f * (c0 * c0 + c1 * c1 + c2 * c2);

    unsigned short h0 = bf16_rne(c0), h1 = bf16_rne(c1), h2 = bf16_rne(c2);
    unsigned short l0 = bf16_rne(c0 - bf16_f(h0));
    unsigned short l1 = bf16_rne(c1 - bf16_f(h1));
    unsigned short l2 = bf16_rne(c2 - bf16_f(h2));
    unsigned short hh = bf16_rne(h);
    unsigned short hl = bf16_rne(h - bf16_f(hh));

    u16x8 blo, bhi;
    blo[0]=h0; blo[1]=h1; blo[2]=h2; blo[3]=h0; blo[4]=h1; blo[5]=h2; blo[6]=l0; blo[7]=l1;
    bhi[0]=l2; bhi[1]=hh; bhi[2]=hl; bhi[3]=0; bhi[4]=0; bhi[5]=0; bhi[6]=0; bhi[7]=0;

    int u = p >> 5, pos = p & 31;
    size_t base = ((size_t)cid << 17) + (size_t)u * 1024 + (size_t)pos * 16;
    *(u16x8*)((char*)Bform + base)       = blo;
    *(u16x8*)((char*)Bform + base + 512) = bhi;

    smax[i] = 0u;        // below any order-mapped float
    if (i == 0) *out = 0.f;
}

// ---------------- pass 1: MFMA chamfer core (R13 loop, in-reg A) ----------------
// grid = 16 (dir,b) * 8 i-blocks * 4 j-quarters = 512 blocks of 256 thr.
__global__ __launch_bounds__(256, 2) void chamfer_mfma(
    const float* __restrict__ x, const float* __restrict__ y,
    const unsigned short* __restrict__ Bform,
    unsigned* __restrict__ smax)
{
    __shared__ float buf[4][64][33];   // 33792 B, per-wave regions

    const int bid  = blockIdx.x;
    const int dirb = bid >> 5;        // 0..15 (A-cloud id)
    const int sub  = bid & 31;
    const int iblk = sub >> 2;        // 0..7
    const int jq   = sub & 3;         // 0..3

    const int tid = threadIdx.x;
    const int w   = tid >> 6;         // wave 0..3
    const int l   = tid & 63;
    const int g   = l >> 5;           // k-half
    const int pos = l & 31;           // row/col within tile

    const float* Araw = (dirb < 8) ? x + (size_t)dirb * NPTS * 3
                                   : y + (size_t)(dirb - 8) * NPTS * 3;
    const char* Bbase = (const char*)Bform + ((size_t)(dirb ^ 8) << 17);

    // ---- A fragments in-register from raw floats (R11-verified pattern) ----
    const int it0 = iblk * 16 + w * 4;
    bf16x8 afr[4];
    #pragma unroll
    for (int t = 0; t < 4; ++t) {
        const float* ap = Araw + (size_t)((it0 + t) * 32 + pos) * 3;
        float c0 = ap[0], c1 = ap[1], c2 = ap[2];
        unsigned short h0 = bf16_rne(c0), h1 = bf16_rne(c1), h2 = bf16_rne(c2);
        unsigned short l0 = bf16_rne(c0 - bf16_f(h0));
        unsigned short l1 = bf16_rne(c1 - bf16_f(h1));
        unsigned short l2 = bf16_rne(c2 - bf16_f(h2));
        const short ONE = (short)0x3F80;
        bf16x8 alo, ahi;
        alo[0]=(short)h0; alo[1]=(short)h1; alo[2]=(short)h2; alo[3]=(short)l0;
        alo[4]=(short)l1; alo[5]=(short)l2; alo[6]=(short)h0; alo[7]=(short)h1;
        ahi[0]=(short)h2; ahi[1]=ONE; ahi[2]=ONE; ahi[3]=0;
        ahi[4]=0; ahi[5]=0; ahi[6]=0; ahi[7]=0;
        #pragma unroll
        for (int e = 0; e < 8; ++e) afr[t][e] = g ? ahi[e] : alo[e];
    }

    f32x16 zc;
    #pragma unroll
    for (int r = 0; r < 16; ++r) zc[r] = 0.f;

    f32x16 run[4];
    #pragma unroll
    for (int t = 0; t < 4; ++t)
        #pragma unroll
        for (int r = 0; r < 16; ++r) run[t][r] = -3.0e38f;

    const char* Bq = Bbase + (size_t)(jq * 32) * 1024
                           + (size_t)g * 512 + (size_t)pos * 16;

    bf16x8 cb0 = *(const bf16x8*)(Bq);
    bf16x8 cb1 = *(const bf16x8*)(Bq + 1024);
    bf16x8 cb2 = *(const bf16x8*)(Bq + 2048);
    bf16x8 cb3 = *(const bf16x8*)(Bq + 3072);

    #pragma unroll 1
    for (int j = 0; j < 32; j += 4) {
        const int jn = (j + 4) & 31;           // branchless wrap prefetch
        const char* Bn = Bq + (size_t)jn * 1024;
        bf16x8 nb0 = *(const bf16x8*)(Bn);
        bf16x8 nb1 = *(const bf16x8*)(Bn + 1024);
        bf16x8 nb2 = *(const bf16x8*)(Bn + 2048);
        bf16x8 nb3 = *(const bf16x8*)(Bn + 3072);

        // pass A: tiles j, j+1
        #pragma unroll
        for (int t = 0; t < 4; ++t) {
            f32x16 d0 = __builtin_amdgcn_mfma_f32_32x32x16_bf16(afr[t], cb0, zc, 0, 0, 0);
            f32x16 d1 = __builtin_amdgcn_mfma_f32_32x32x16_bf16(afr[t], cb1, zc, 0, 0, 0);
            #pragma unroll
            for (int r = 0; r < 16; ++r)
                run[t][r] = fmaxf(fmaxf(d0[r], d1[r]), run[t][r]);   // v_max3_f32
        }
        // pass B: tiles j+2, j+3
        #pragma unroll
        for (int t = 0; t < 4; ++t) {
            f32x16 d2 = __builtin_amdgcn_mfma_f32_32x32x16_bf16(afr[t], cb2, zc, 0, 0, 0);
            f32x16 d3 = __builtin_amdgcn_mfma_f32_32x32x16_bf16(afr[t], cb3, zc, 0, 0, 0);
            #pragma unroll
            for (int r = 0; r < 16; ++r)
                run[t][r] = fmaxf(fmaxf(d2[r], d3[r]), run[t][r]);   // v_max3_f32
        }
        cb0 = nb0; cb1 = nb1; cb2 = nb2; cb3 = nb3;
    }

    // ---- epilogue, 2 phases of 2 i-tiles each (verified R9/R13) ----
    #pragma unroll
    for (int ph = 0; ph < 2; ++ph) {
        if (ph) __syncthreads();   // phase-0 reads done before overwrite
        #pragma unroll
        for (int tl = 0; tl < 2; ++tl) {
            const int t = 2 * ph + tl;
            #pragma unroll
            for (int r = 0; r < 16; ++r) {
                int rowin = (r & 3) + 8 * (r >> 2) + 4 * g;   // verified C/D map
                buf[w][tl * 32 + rowin][pos] = run[t][r];
            }
        }
        __syncthreads();

        float m = buf[w][l][0];
        #pragma unroll
        for (int k = 1; k < 32; ++k) m = fmaxf(m, buf[w][l][k]);
        int idx = dirb * 4096 + iblk * 512 + w * 128 + 2 * ph * 32 + l;
        unsigned bits = __float_as_uint(m);
        unsigned mu = (bits & 0x80000000u) ? ~bits : (bits | 0x80000000u);
        atomicMax(&smax[idx], mu);
    }
}

// ---------------- pass 2: unmap, add h_a from raw, sum ----------------
__global__ __launch_bounds__(256) void reduce_kernel(
    const unsigned* __restrict__ smax,
    const float* __restrict__ x, const float* __restrict__ y,
    float* __restrict__ out)
{
    const int stride = 64 * 256;
    int tid = blockIdx.x * 256 + threadIdx.x;
    float s = 0.f;
    for (int k = tid; k < TOT; k += stride) {
        unsigned u = smax[k];
        unsigned bits = (u & 0x80000000u) ? (u & 0x7FFFFFFFu) : ~u;
        int cid = k >> 12, p = k & 4095;
        const float* ap = (cid < 8) ? x + ((size_t)cid * NPTS + p) * 3
                                    : y + ((size_t)(cid - 8) * NPTS + p) * 3;
        float a0 = ap[0], a1 = ap[1], a2 = ap[2];
        s += __uint_as_float(bits) - 0.5f * (a0 * a0 + a1 * a1 + a2 * a2);
    }

    #pragma unroll
    for (int off = 32; off > 0; off >>= 1)
        s += __shfl_down(s, off);

    __shared__ float redb[4];
    const int lane = threadIdx.x & 63, wave = threadIdx.x >> 6;
    if (lane == 0) redb[wave] = s;
    __syncthreads();
    if (threadIdx.x == 0) {
        float t = redb[0] + redb[1] + redb[2] + redb[3];
        // min_d = -2*(smax + h_a); loss = 0.005 * sum / 32768
        atomicAdd(out, t * (-2.0f * 0.005f / 32768.f));
    }
}

extern "C" void kernel_launch(void* const* d_in, const int* in_sizes, int n_in,
                              void* d_out, int out_size, void* d_ws, size_t ws_size,
                              hipStream_t stream) {
    const float* x = (const float*)d_in[0];
    const float* y = (const float*)d_in[1];
    float* out = (float*)d_out;

    unsigned short* Bform = (unsigned short*)d_ws;                       // 2 MB
    unsigned*       smax  = (unsigned*)((char*)d_ws + (2u << 20));       // 256 KB

    prep_b<<<dim3(TOT / 256), dim3(256), 0, stream>>>(x, y, Bform, smax, out);
    chamfer_mfma<<<dim3(512), dim3(256), 0, stream>>>(x, y, Bform, smax);
    reduce_kernel<<<dim3(64), dim3(256), 0, stream>>>(smax, x, y, out);
}

// Round 16
// 69.758 us; speedup vs baseline: 1.1379x; 1.0092x over previous
//
#include <hip/hip_runtime.h>

#define NPTS 4096
#define NB   8
#define TOT  (2 * NB * NPTS)   // 65536 rows (dir*batch*point)

typedef __attribute__((ext_vector_type(8)))  short          bf16x8;
typedef __attribute__((ext_vector_type(8)))  unsigned short u16x8;
typedef __attribute__((ext_vector_type(16))) float          f32x16;

__device__ __forceinline__ unsigned short bf16_rne(float f) {
    unsigned u = __float_as_uint(f);
    u += 0x7FFFu + ((u >> 16) & 1u);
    return (unsigned short)(u >> 16);
}
__device__ __forceinline__ float bf16_f(unsigned short s) {
    return __uint_as_float(((unsigned)s) << 16);
}

// s(i,j) = ah.bh(3) + al.bh(3) + ah.bl(3) + 1*hh + 1*hl   (11 K-slots of 16)
// A slots: [ah0,ah1,ah2, al0,al1,al2, ah0,ah1 | ah2, 1, 1, 0,0,0,0,0]
// B slots: [bh0,bh1,bh2, bh0,bh1,bh2, bl0,bl1 | bl2, hh, hl, 0,0,0,0,0]
// 32x32x16 operand layout: lane l -> point (32u + (l&31)), k-slots 8*(l>>5)..+7.
// All verified on-HW R7/R9/R13/R15 (absmax ~0).

// ---------------- pass 0: B fragments + smax init + out init ----------------
__global__ __launch_bounds__(256) void prep_b(
    const float* __restrict__ x, const float* __restrict__ y,
    unsigned short* __restrict__ Bform, unsigned* __restrict__ smax,
    float* __restrict__ out)
{
    int i   = blockIdx.x * 256 + threadIdx.x;   // 0..65535
    int cid = i >> 12;                          // 0..7: x[b], 8..15: y[b]
    int p   = i & 4095;
    const float* src = (cid < 8) ? x + ((size_t)cid * NPTS + p) * 3
                                 : y + ((size_t)(cid - 8) * NPTS + p) * 3;
    float c0 = src[0], c1 = src[1], c2 = src[2];
    float h  = -0.5f * (c0 * c0 + c1 * c1 + c2 * c2);

    unsigned short h0 = bf16_rne(c0), h1 = bf16_rne(c1), h2 = bf16_rne(c2);
    unsigned short l0 = bf16_rne(c0 - bf16_f(h0));
    unsigned short l1 = bf16_rne(c1 - bf16_f(h1));
    unsigned short l2 = bf16_rne(c2 - bf16_f(h2));
    unsigned short hh = bf16_rne(h);
    unsigned short hl = bf16_rne(h - bf16_f(hh));

    u16x8 blo, bhi;
    blo[0]=h0; blo[1]=h1; blo[2]=h2; blo[3]=h0; blo[4]=h1; blo[5]=h2; blo[6]=l0; blo[7]=l1;
    bhi[0]=l2; bhi[1]=hh; bhi[2]=hl; bhi[3]=0; bhi[4]=0; bhi[5]=0; bhi[6]=0; bhi[7]=0;

    int u = p >> 5, pos = p & 31;
    size_t base = ((size_t)cid << 17) + (size_t)u * 1024 + (size_t)pos * 16;
    *(u16x8*)((char*)Bform + base)       = blo;
    *(u16x8*)((char*)Bform + base + 512) = bhi;

    smax[i] = 0u;        // below any order-mapped float
    if (i == 0) *out = 0.f;
}

// ---------------- pass 1: MFMA chamfer core, software-pipelined max ----------
// grid = 16 (dir,b) * 8 i-blocks * 4 j-quarters = 512 blocks of 256 thr.
// R16 change vs R15: consumption (v_max3) of each MFMA pair is deferred one
// stage — stage k issues mfma(afr[t_k]) then folds stage k-1's results into
// run[t_{k-1}] — putting ~48+ cycles between MFMA issue and register read to
// cover MFMA result latency (the diagnosed ~50% SIMD idle at 2 waves/SIMD).
__global__ __launch_bounds__(256, 2) void chamfer_mfma(
    const float* __restrict__ x, const float* __restrict__ y,
    const unsigned short* __restrict__ Bform,
    unsigned* __restrict__ smax)
{
    __shared__ float buf[4][64][33];   // 33792 B, per-wave regions

    const int bid  = blockIdx.x;
    const int dirb = bid >> 5;        // 0..15 (A-cloud id)
    const int sub  = bid & 31;
    const int iblk = sub >> 2;        // 0..7
    const int jq   = sub & 3;         // 0..3

    const int tid = threadIdx.x;
    const int w   = tid >> 6;         // wave 0..3
    const int l   = tid & 63;
    const int g   = l >> 5;           // k-half
    const int pos = l & 31;           // row/col within tile

    const float* Araw = (dirb < 8) ? x + (size_t)dirb * NPTS * 3
                                   : y + (size_t)(dirb - 8) * NPTS * 3;
    const char* Bbase = (const char*)Bform + ((size_t)(dirb ^ 8) << 17);

    // ---- A fragments in-register from raw floats (R11/R15-verified) ----
    const int it0 = iblk * 16 + w * 4;
    bf16x8 afr[4];
    #pragma unroll
    for (int t = 0; t < 4; ++t) {
        const float* ap = Araw + (size_t)((it0 + t) * 32 + pos) * 3;
        float c0 = ap[0], c1 = ap[1], c2 = ap[2];
        unsigned short h0 = bf16_rne(c0), h1 = bf16_rne(c1), h2 = bf16_rne(c2);
        unsigned short l0 = bf16_rne(c0 - bf16_f(h0));
        unsigned short l1 = bf16_rne(c1 - bf16_f(h1));
        unsigned short l2 = bf16_rne(c2 - bf16_f(h2));
        const short ONE = (short)0x3F80;
        bf16x8 alo, ahi;
        alo[0]=(short)h0; alo[1]=(short)h1; alo[2]=(short)h2; alo[3]=(short)l0;
        alo[4]=(short)l1; alo[5]=(short)l2; alo[6]=(short)h0; alo[7]=(short)h1;
        ahi[0]=(short)h2; ahi[1]=ONE; ahi[2]=ONE; ahi[3]=0;
        ahi[4]=0; ahi[5]=0; ahi[6]=0; ahi[7]=0;
        #pragma unroll
        for (int e = 0; e < 8; ++e) afr[t][e] = g ? ahi[e] : alo[e];
    }

    f32x16 zc;
    #pragma unroll
    for (int r = 0; r < 16; ++r) zc[r] = 0.f;

    f32x16 run[4];
    #pragma unroll
    for (int t = 0; t < 4; ++t)
        #pragma unroll
        for (int r = 0; r < 16; ++r) run[t][r] = -3.0e38f;

    // pipeline registers: previous stage's MFMA results (dummy-initialized;
    // first consume folds -3e38 into run[3] — harmless, run starts at -3e38)
    f32x16 p0, p1;
    #pragma unroll
    for (int r = 0; r < 16; ++r) { p0[r] = -3.0e38f; p1[r] = -3.0e38f; }

    const char* Bq = Bbase + (size_t)(jq * 32) * 1024
                           + (size_t)g * 512 + (size_t)pos * 16;

    bf16x8 cb0 = *(const bf16x8*)(Bq);
    bf16x8 cb1 = *(const bf16x8*)(Bq + 1024);
    bf16x8 cb2 = *(const bf16x8*)(Bq + 2048);
    bf16x8 cb3 = *(const bf16x8*)(Bq + 3072);

    // stage: issue 2 MFMAs with afr[T] against (B0,B1), then consume the
    // PREVIOUS stage's pair into run[RP] (= previous stage's T), rotate p.
#define STAGE(T, B0, B1, RP)                                                    \
    {                                                                           \
        f32x16 d0 = __builtin_amdgcn_mfma_f32_32x32x16_bf16(afr[T], B0, zc, 0, 0, 0); \
        f32x16 d1 = __builtin_amdgcn_mfma_f32_32x32x16_bf16(afr[T], B1, zc, 0, 0, 0); \
        _Pragma("unroll")                                                       \
        for (int r = 0; r < 16; ++r)                                            \
            run[RP][r] = fmaxf(fmaxf(p0[r], p1[r]), run[RP][r]);                \
        p0 = d0; p1 = d1;                                                       \
    }

    #pragma unroll 1
    for (int j = 0; j < 32; j += 4) {
        bf16x8 nb0, nb1, nb2, nb3;
        if (j < 28) {                       // wave-uniform scalar branch
            const char* Bn = Bq + (size_t)(j + 4) * 1024;
            nb0 = *(const bf16x8*)(Bn);
            nb1 = *(const bf16x8*)(Bn + 1024);
            nb2 = *(const bf16x8*)(Bn + 2048);
            nb3 = *(const bf16x8*)(Bn + 3072);
        }
        // 8 stages/iter; consume target = previous stage's t = (stage-1)&3
        STAGE(0, cb0, cb1, 3)
        STAGE(1, cb0, cb1, 0)
        STAGE(2, cb0, cb1, 1)
        STAGE(3, cb0, cb1, 2)
        STAGE(0, cb2, cb3, 3)
        STAGE(1, cb2, cb3, 0)
        STAGE(2, cb2, cb3, 1)
        STAGE(3, cb2, cb3, 2)
        if (j < 28) { cb0 = nb0; cb1 = nb1; cb2 = nb2; cb3 = nb3; }
    }
#undef STAGE

    // drain: last stage used afr[3]
    #pragma unroll
    for (int r = 0; r < 16; ++r)
        run[3][r] = fmaxf(fmaxf(p0[r], p1[r]), run[3][r]);

    // ---- epilogue, 2 phases of 2 i-tiles each (verified R9/R13/R15) ----
    #pragma unroll
    for (int ph = 0; ph < 2; ++ph) {
        if (ph) __syncthreads();   // phase-0 reads done before overwrite
        #pragma unroll
        for (int tl = 0; tl < 2; ++tl) {
            const int t = 2 * ph + tl;
            #pragma unroll
            for (int r = 0; r < 16; ++r) {
                int rowin = (r & 3) + 8 * (r >> 2) + 4 * g;   // verified C/D map
                buf[w][tl * 32 + rowin][pos] = run[t][r];
            }
        }
        __syncthreads();

        float m = buf[w][l][0];
        #pragma unroll
        for (int k = 1; k < 32; ++k) m = fmaxf(m, buf[w][l][k]);
        int idx = dirb * 4096 + iblk * 512 + w * 128 + 2 * ph * 32 + l;
        unsigned bits = __float_as_uint(m);
        unsigned mu = (bits & 0x80000000u) ? ~bits : (bits | 0x80000000u);
        atomicMax(&smax[idx], mu);
    }
}

// ---------------- pass 2: unmap, add h_a from raw, sum ----------------
__global__ __launch_bounds__(256) void reduce_kernel(
    const unsigned* __restrict__ smax,
    const float* __restrict__ x, const float* __restrict__ y,
    float* __restrict__ out)
{
    const int stride = 64 * 256;
    int tid = blockIdx.x * 256 + threadIdx.x;
    float s = 0.f;
    for (int k = tid; k < TOT; k += stride) {
        unsigned u = smax[k];
        unsigned bits = (u & 0x80000000u) ? (u & 0x7FFFFFFFu) : ~u;
        int cid = k >> 12, p = k & 4095;
        const float* ap = (cid < 8) ? x + ((size_t)cid * NPTS + p) * 3
                                    : y + ((size_t)(cid - 8) * NPTS + p) * 3;
        float a0 = ap[0], a1 = ap[1], a2 = ap[2];
        s += __uint_as_float(bits) - 0.5f * (a0 * a0 + a1 * a1 + a2 * a2);
    }

    #pragma unroll
    for (int off = 32; off > 0; off >>= 1)
        s += __shfl_down(s, off);

    __shared__ float redb[4];
    const int lane = threadIdx.x & 63, wave = threadIdx.x >> 6;
    if (lane == 0) redb[wave] = s;
    __syncthreads();
    if (threadIdx.x == 0) {
        float t = redb[0] + redb[1] + redb[2] + redb[3];
        // min_d = -2*(smax + h_a); loss = 0.005 * sum / 32768
        atomicAdd(out, t * (-2.0f * 0.005f / 32768.f));
    }
}

extern "C" void kernel_launch(void* const* d_in, const int* in_sizes, int n_in,
                              void* d_out, int out_size, void* d_ws, size_t ws_size,
                              hipStream_t stream) {
    const float* x = (const float*)d_in[0];
    const float* y = (const float*)d_in[1];
    float* out = (float*)d_out;

    unsigned short* Bform = (unsigned short*)d_ws;                       // 2 MB
    unsigned*       smax  = (unsigned*)((char*)d_ws + (2u << 20));       // 256 KB

    prep_b<<<dim3(TOT / 256), dim3(256), 0, stream>>>(x, y, Bform, smax, out);
    chamfer_mfma<<<dim3(512), dim3(256), 0, stream>>>(x, y, Bform, smax);
    reduce_kernel<<<dim3(64), dim3(256), 0, stream>>>(smax, x, y, out);
}